// Round 6
// baseline (336.225 us; speedup 1.0000x reference)
//
#include <hip/hip_runtime.h>
#include <hip/hip_bf16.h>
#include <cstdint>

// MultiHeadSelfAttention: B=4, N=2048, C=1024, H=16, D=64
// R12: attn T5 setprio (kept).
// R13: gemm_qkv 8-phase 256x192. 87.5us = no change; conflicts 0, VALU halved.
// R14: XCD-cohort map: FETCH 134->41MB but 96.8us (worse). All pipes idle,
//  MfmaUtil 20.7 -> latency/sync-bound at 1 block/CU, not BW/conflict-bound.
// R15: gemm_qkv back to 2-phase 128x128 (R12 skeleton) but A-ONLY LDS
//  staging (16KB); B (weights, L2-hot) read direct global->reg as native
//  MFMA frags (lane16=col, quad*8=k). Halves the barrier-drained staging
//  volume, cuts LDS ops/iter 24->16, restores 3-4 blocks/CU TLP.
// R16: identical resubmit of R15 — round 5 was an infra failure (container
//  failed twice); R15 is still unbenched.

typedef __attribute__((ext_vector_type(8))) short short8;    // 8 bf16
typedef __attribute__((ext_vector_type(4))) float floatx4;

#if __has_builtin(__builtin_amdgcn_exp2f)
#define EXP2F(x) __builtin_amdgcn_exp2f(x)
#else
#define EXP2F(x) __expf((x) * 0.6931471805599453f)
#endif

__device__ __forceinline__ unsigned short f2bf(float f) {
  unsigned u = __float_as_uint(f);
  unsigned r = u + 0x7fffu + ((u >> 16) & 1u);   // RNE
  return (unsigned short)(r >> 16);
}

__device__ __forceinline__ void async16(const void* g, void* l) {
  __builtin_amdgcn_global_load_lds(
      (__attribute__((address_space(1))) void*)(void*)(uintptr_t)g,
      (__attribute__((address_space(3))) void*)l, 16, 0, 0);
}

// ------------------------------------------- prep: x cvt + 4x W^T (merged)
__global__ __launch_bounds__(256) void prep_kernel(
    const float* __restrict__ x, unsigned short* __restrict__ xb,
    const float* __restrict__ W0, const float* __restrict__ W1,
    const float* __restrict__ W2, const float* __restrict__ W3,
    unsigned short* __restrict__ T0, unsigned short* __restrict__ T1,
    unsigned short* __restrict__ T2, unsigned short* __restrict__ T3) {
  const int tid = threadIdx.x;
  int blk = blockIdx.x;
  if (blk < 8192) {               // ---- x f32 -> bf16
    int i = (blk * 256 + tid) * 4;
    float4 v = *(const float4*)(x + i);
    ushort4 o;
    o.x = f2bf(v.x); o.y = f2bf(v.y); o.z = f2bf(v.z); o.w = f2bf(v.w);
    *(ushort4*)(xb + i) = o;
  } else {                        // ---- W transpose+convert, 32x32 tiles
    int t = blk - 8192;
    int z = t >> 10, tile = t & 1023;
    const float* W = z == 0 ? W0 : z == 1 ? W1 : z == 2 ? W2 : W3;
    unsigned short* T = z == 0 ? T0 : z == 1 ? T1 : z == 2 ? T2 : T3;
    __shared__ float tb[32][33];
    int tx = tid & 31, ty = tid >> 5;            // 32 x 8
    int bx = (tile & 31) * 32, by = (tile >> 5) * 32;
#pragma unroll
    for (int i = 0; i < 4; ++i)
      tb[ty + i * 8][tx] = W[(size_t)(by + ty + i * 8) * 1024 + bx + tx];
    __syncthreads();
#pragma unroll
    for (int i = 0; i < 4; ++i)
      T[(size_t)(bx + ty + i * 8) * 1024 + by + tx] = f2bf(tb[tx][ty + i * 8]);
  }
}

// ------------------------------------------- fused QKV projection (M x 3072)
// 128x128 tile, 4 waves, 2-phase. A-only LDS (16KB, [half][row][32]);
// B-frags direct global->reg (BT is [n][k]: lane16=col row, quad*8=k off).
__global__ __launch_bounds__(256) void gemm_qkv(
    const unsigned short* __restrict__ A, const unsigned short* __restrict__ BT,
    const float* __restrict__ bq, const float* __restrict__ bk,
    const float* __restrict__ bv,
    unsigned short* __restrict__ Qo, unsigned short* __restrict__ Ko,
    unsigned short* __restrict__ Vo) {
  constexpr int Kd = 1024;
  __shared__ unsigned short As[2 * 128 * 32];   // 16 KB
  const int tid = threadIdx.x;
  const int wave = tid >> 6, lane = tid & 63;
  const int quad = lane >> 4, l16 = lane & 15;
  const int wm = (wave & 1) * 64, wn = (wave >> 1) * 64;
  const int m0 = blockIdx.x * 128, n0 = blockIdx.y * 128;
  const int mid = blockIdx.y >> 3;                 // 0=Q 1=K 2=V
  const float* bias = mid == 0 ? bq : mid == 1 ? bk : bv;
  const float scale = mid == 0 ? 0.180336880021082f : 1.0f;  // Q: 0.125*log2(e)

  floatx4 acc[4][4] = {};
  const unsigned short* Ag = A + (size_t)m0 * Kd;
  // per-lane B row base: col = n0 + wn + j*16 + l16  (j via offset)
  const unsigned short* Bl = BT + ((size_t)n0 + wn + l16) * Kd + quad * 8;

  for (int k0 = 0; k0 < Kd; k0 += 64) {
    __syncthreads();
    // stage A tile (128 rows x 64 k) -> LDS, 4 async16 per wave
#pragma unroll
    for (int p = 0; p < 4; ++p) {
      int c = (wave * 4 + p) * 64 + lane;
      int h = c >> 9, row = (c >> 2) & 127, kp = c & 3;
      async16(Ag + (size_t)row * Kd + k0 + h * 32 + kp * 8,
              (char*)As + (size_t)(wave * 4 + p) * 1024);
    }
    // B-frags for this K-step, direct to regs (L2-hot weights)
    short8 b[4][2];
#pragma unroll
    for (int j = 0; j < 4; ++j)
#pragma unroll
      for (int ks = 0; ks < 2; ++ks)
        b[j][ks] = *(const short8*)(Bl + (size_t)j * 16 * Kd + k0 + ks * 32);
    __syncthreads();   // drains A-stages (vmcnt) + B-loads complete
#pragma unroll
    for (int ks = 0; ks < 2; ++ks) {
      short8 a[4];
#pragma unroll
      for (int i = 0; i < 4; ++i)
        a[i] = *(const short8*)(As + ks * 4096 + (wm + i * 16 + l16) * 32 + quad * 8);
#pragma unroll
      for (int i = 0; i < 4; ++i)
#pragma unroll
        for (int j = 0; j < 4; ++j)
          acc[i][j] = __builtin_amdgcn_mfma_f32_16x16x32_bf16(a[i], b[j][ks], acc[i][j], 0, 0, 0);
    }
  }

#pragma unroll
  for (int j = 0; j < 4; ++j) {
    int gcol = n0 + wn + j * 16 + l16;
    int cn = gcol & 1023;
    float bb = bias[cn];
    int h = cn >> 6, d = cn & 63;
#pragma unroll
    for (int i = 0; i < 4; ++i) {
      int rbase = m0 + wm + i * 16 + quad * 4;
#pragma unroll
      for (int r = 0; r < 4; ++r) {
        int row = rbase + r;
        unsigned short hv = f2bf((acc[i][j][r] + bb) * scale);
        int bi = row >> 11, ni = row & 2047;
        size_t bh = (size_t)bi * 16 + h;
        if (mid == 2) {   // V^T B-frag, key order interleaved: pos=(jk&15)*2|(jk>>4)
          int nt = d >> 4, vl = d & 15;
          int kq = ni >> 5, jk = ni & 31;
          int pos = ((jk & 15) << 1) | (jk >> 4);
          Vo[((bh * 64 + kq) * 4 + nt) * 512 + (pos >> 3) * 128 + vl * 8 + (pos & 7)] = hv;
        } else {          // Q/K frag: block (bh*128 + tok16)*2 + kk
          int kfg = ni >> 4, tl = ni & 15;
          int kk = d >> 5, dq = (d & 31) >> 3, dj = d & 7;
          unsigned short* outp = mid == 0 ? Qo : Ko;
          outp[((bh * 128 + kfg) * 2 + kk) * 512 + dq * 128 + tl * 8 + dj] = hv;
        }
      }
    }
  }
}

// --------------------------------------------------------------- attention
// Block: 4 waves = 2 q-groups (32 rows) x 2 key-halves (32 kt each).
// Grid 2048. No barriers in main loop. P parity double-buffer + K-frag
// register prefetch. R12: setprio(1) around MFMA clusters (T5, m191 regime).
__global__ __launch_bounds__(256, 3) void attn_kernel(
    const unsigned short* __restrict__ Qs, const unsigned short* __restrict__ Ksw,
    const unsigned short* __restrict__ Vsw, unsigned short* __restrict__ O) {
  __shared__ __align__(16) char smem[20480];

  const int tid = threadIdx.x, wave = tid >> 6, lane = tid & 63;
  const int quad = lane >> 4, l16 = lane & 15;
  const int wk = wave & 1, wqi = wave >> 1;
  int blk = blockIdx.x;
  int xcd = blk & 7, slot = blk >> 3;
  int bh = (slot & 7) * 8 + xcd, qb = slot >> 3;   // qb: 0..31 (64-row blocks)

  unsigned short* Pw0 = (unsigned short*)(smem + wave * 5120);
  unsigned short* Pw1 = (unsigned short*)(smem + wave * 5120 + 2560);

  // Q A-frags (2 row-tiles x 2 k-halves)
  short8 aq[2][2];
#pragma unroll
  for (int rt = 0; rt < 2; ++rt)
#pragma unroll
    for (int kk = 0; kk < 2; ++kk)
      aq[rt][kk] = *(const short8*)(Qs +
          (((size_t)bh * 128 + qb * 4 + wqi * 2 + rt) * 2 + kk) * 512 + lane * 8);

  short8 ones;
#pragma unroll
  for (int i = 0; i < 8; ++i) ones[i] = (short)0x3F80;   // bf16 1.0

  const float MSUB = 17.3123404906675611f;   // 12*log2(e); scores in log2 units
  floatx4 mneg;
#pragma unroll
  for (int i = 0; i < 4; ++i) mneg[i] = -MSUB;

  floatx4 acc_o[2][4] = {};
  floatx4 acc_l[2] = {};

  const unsigned short* kptr0 = Ksw + (size_t)bh * 128 * 2 * 512 + (size_t)wk * 32 * 2048;
  const unsigned short* vptr0 = Vsw + (size_t)bh * 64 * 4 * 512 + (size_t)wk * 32 * 2048;

  short8 kf0[2][2], kf1[2][2], vf[4];
  floatx4 sacc[2][2];

#define LOAD_KF(dst, KT)                                                          \
  {                                                                               \
    _Pragma("unroll") for (int ct = 0; ct < 2; ++ct)                              \
        _Pragma("unroll") for (int kk = 0; kk < 2; ++kk)                          \
            dst[ct][kk] = *(const short8*)(kptr0 + (size_t)(KT)*2048 +            \
                                           (ct * 2 + kk) * 512 + lane * 8);       \
  }
#define LOAD_VF(KT)                                                               \
  {                                                                               \
    _Pragma("unroll") for (int nt = 0; nt < 4; ++nt)                              \
        vf[nt] = *(const short8*)(vptr0 + (size_t)(KT)*2048 + nt * 512 + lane * 8); \
  }
#define QK_BLOCK(KF)                                                              \
  {                                                                               \
    __builtin_amdgcn_s_setprio(1);                                                \
    _Pragma("unroll") for (int rt = 0; rt < 2; ++rt)                              \
        _Pragma("unroll") for (int ct = 0; ct < 2; ++ct) {                        \
      sacc[rt][ct] = __builtin_amdgcn_mfma_f32_16x16x32_bf16(aq[rt][0], KF[ct][0], mneg, 0, 0, 0); \
      sacc[rt][ct] = __builtin_amdgcn_mfma_f32_16x16x32_bf16(aq[rt][1], KF[ct][1], sacc[rt][ct], 0, 0, 0); \
    }                                                                             \
    __builtin_amdgcn_s_setprio(0);                                                \
  }
#define EXP_WRITE(PBUF)                                                           \
  {                                                                               \
    _Pragma("unroll") for (int rt = 0; rt < 2; ++rt)                              \
        _Pragma("unroll") for (int r = 0; r < 4; ++r) {                           \
      float pe = EXP2F(sacc[rt][0][r]);                                           \
      float po = EXP2F(sacc[rt][1][r]);                                           \
      unsigned pk = __builtin_amdgcn_perm(__float_as_uint(po), __float_as_uint(pe), 0x07060302u); \
      ((unsigned*)((PBUF) + (rt * 16 + quad * 4 + r) * 40))[l16] = pk;            \
    }                                                                             \
  }
#define PV_BLOCK(PBUF)                                                            \
  {                                                                               \
    __builtin_amdgcn_s_setprio(1);                                                \
    _Pragma("unroll") for (int rt = 0; rt < 2; ++rt) {                            \
      short8 ap = *(const short8*)((PBUF) + (rt * 16 + l16) * 40 + quad * 8);     \
      acc_l[rt] = __builtin_amdgcn_mfma_f32_16x16x32_bf16(ap, ones, acc_l[rt], 0, 0, 0); \
      _Pragma("unroll") for (int nt = 0; nt < 4; ++nt)                            \
          acc_o[rt][nt] = __builtin_amdgcn_mfma_f32_16x16x32_bf16(ap, vf[nt], acc_o[rt][nt], 0, 0, 0); \
    }                                                                             \
    __builtin_amdgcn_s_setprio(0);                                                \
  }

  // ---- prologue: kt=0 (kf0), prefetch kt=1 (kf1), vf=V(0)
  LOAD_KF(kf0, 0);
  LOAD_KF(kf1, 1);
  LOAD_VF(0);
  QK_BLOCK(kf0);
  EXP_WRITE(Pw0);

  // ---- main: i = 2it+1 (odd: cur=kf1, next->kf0, Pprev=Pw0, Pcur=Pw1)
  //            i = 2it+2 (even: cur=kf0, next->kf1, Pprev=Pw1, Pcur=Pw0)
  for (int it = 0; it < 15; ++it) {
    const int i1 = 2 * it + 1, i2 = 2 * it + 2;
    // odd sub-iter
    LOAD_KF(kf0, i1 + 1);
    QK_BLOCK(kf1);
    PV_BLOCK(Pw0);          // PV(i1-1) with vf = V(i1-1)
    LOAD_VF(i1);
    EXP_WRITE(Pw1);
    // even sub-iter
    LOAD_KF(kf1, i2 + 1);
    QK_BLOCK(kf0);
    PV_BLOCK(Pw1);          // PV(i2-1)
    LOAD_VF(i2);
    EXP_WRITE(Pw0);
  }
  // ---- tail: i = 31 (odd roles, no prefetch)
  QK_BLOCK(kf1);
  PV_BLOCK(Pw0);            // PV(30)
  LOAD_VF(31);
  EXP_WRITE(Pw1);
  PV_BLOCK(Pw1);            // PV(31)

#undef LOAD_KF
#undef LOAD_VF
#undef QK_BLOCK
#undef EXP_WRITE
#undef PV_BLOCK

  // ---- combine key halves, normalize, store
  float* buf = (float*)smem + wqi * 2176;          // 32 x 68 f32
  float* lbuf = (float*)(smem + 17408);            // 64 f32
  __syncthreads();
  if (wk == 1) {
#pragma unroll
    for (int rt = 0; rt < 2; ++rt)
#pragma unroll
      for (int r = 0; r < 4; ++r) {
        int row = rt * 16 + quad * 4 + r;
#pragma unroll
        for (int nt = 0; nt < 4; ++nt)
          buf[row * 68 + nt * 16 + l16] = acc_o[rt][nt][r];
        if (l16 == 0) lbuf[wqi * 32 + row] = acc_l[rt][r];
      }
  }
  __syncthreads();
  if (wk == 0) {
    const int b = bh >> 4, h = bh & 15;
#pragma unroll
    for (int rt = 0; rt < 2; ++rt)
#pragma unroll
      for (int r = 0; r < 4; ++r) {
        int row = rt * 16 + quad * 4 + r;
        float linv = 1.0f / (acc_l[rt][r] + lbuf[wqi * 32 + row]);
        int grow = qb * 64 + wqi * 32 + row;
#pragma unroll
        for (int nt = 0; nt < 4; ++nt) {
          float v = (acc_o[rt][nt][r] + buf[row * 68 + nt * 16 + l16]) * linv;
          O[((size_t)b * 2048 + grow) * 1024 + h * 64 + nt * 16 + l16] = f2bf(v);
        }
      }
  }
}

// ------------------------------------------------------------- output GEMM
// BK=64, same staging as R10.
__global__ __launch_bounds__(256) void gemm_out(
    const unsigned short* __restrict__ A, const unsigned short* __restrict__ BT,
    const float* __restrict__ bias, float* __restrict__ of) {
  constexpr int Kd = 1024;
  __shared__ unsigned short As[2 * 128 * 32];
  __shared__ unsigned short Bs[2 * 128 * 32];
  const int tid = threadIdx.x;
  const int wave = tid >> 6, lane = tid & 63;
  const int quad = lane >> 4, l16 = lane & 15;
  const int wm = (wave & 1) * 64, wn = (wave >> 1) * 64;
  const int m0 = blockIdx.x * 128, n0 = blockIdx.y * 128;

  floatx4 acc[4][4] = {};
  const unsigned short* Ag = A + (size_t)m0 * Kd;
  const unsigned short* Bg = BT + (size_t)n0 * Kd;

  for (int k0 = 0; k0 < Kd; k0 += 64) {
    __syncthreads();
#pragma unroll
    for (int p = 0; p < 4; ++p) {
      int c = (wave * 4 + p) * 64 + lane;
      int h = c >> 9, row = (c >> 2) & 127, kp = c & 3;
      async16(Ag + (size_t)row * Kd + k0 + h * 32 + kp * 8, (char*)As + (size_t)(wave * 4 + p) * 1024);
      async16(Bg + (size_t)row * Kd + k0 + h * 32 + kp * 8, (char*)Bs + (size_t)(wave * 4 + p) * 1024);
    }
    __syncthreads();
#pragma unroll
    for (int ks = 0; ks < 2; ++ks) {
      short8 a[4], b[4];
#pragma unroll
      for (int i = 0; i < 4; ++i) {
        a[i] = *(const short8*)(As + ks * 4096 + (wm + i * 16 + l16) * 32 + quad * 8);
        b[i] = *(const short8*)(Bs + ks * 4096 + (wn + i * 16 + l16) * 32 + quad * 8);
      }
#pragma unroll
      for (int i = 0; i < 4; ++i)
#pragma unroll
        for (int j = 0; j < 4; ++j)
          acc[i][j] = __builtin_amdgcn_mfma_f32_16x16x32_bf16(a[i], b[j], acc[i][j], 0, 0, 0);
    }
  }

#pragma unroll
  for (int j = 0; j < 4; ++j) {
    int col = n0 + wn + j * 16 + l16;
    float bb = bias[col];
#pragma unroll
    for (int i = 0; i < 4; ++i) {
      int rbase = m0 + wm + i * 16 + quad * 4;
#pragma unroll
      for (int r = 0; r < 4; ++r)
        of[(size_t)(rbase + r) * 1024 + col] = acc[i][j][r] + bb;
    }
  }
}

// ---------------------------------------------------------------- launch
extern "C" void kernel_launch(void* const* d_in, const int* in_sizes, int n_in,
                              void* d_out, int out_size, void* d_ws, size_t ws_size,
                              hipStream_t stream) {
  const float* x  = (const float*)d_in[0];
  const float* Wq = (const float*)d_in[1];
  const float* bq = (const float*)d_in[2];
  const float* Wk = (const float*)d_in[3];
  const float* bk = (const float*)d_in[4];
  const float* Wv = (const float*)d_in[5];
  const float* bv = (const float*)d_in[6];
  const float* Wo = (const float*)d_in[7];
  const float* bo = (const float*)d_in[8];

  char* ws = (char*)d_ws;
  unsigned short* xb  = (unsigned short*)(ws);                 // 16 MiB
  unsigned short* wqt = (unsigned short*)(ws + (16u << 20));   // 2 MiB each, contiguous
  unsigned short* wkt = (unsigned short*)(ws + (18u << 20));
  unsigned short* wvt = (unsigned short*)(ws + (20u << 20));
  unsigned short* wot = (unsigned short*)(ws + (22u << 20));
  unsigned short* Qb  = (unsigned short*)(ws + (24u << 20));   // 16 MiB each
  unsigned short* Kb  = (unsigned short*)(ws + (40u << 20));
  unsigned short* Vtb = (unsigned short*)(ws + (56u << 20));
  unsigned short* Ob  = (unsigned short*)(ws + (72u << 20));   // total 88 MiB

  prep_kernel<<<dim3(12288), 256, 0, stream>>>(x, xb, Wq, Wk, Wv, Wo, wqt, wkt, wvt, wot);
  gemm_qkv<<<dim3(64, 24), 256, 0, stream>>>(xb, wqt, bq, bk, bv, Qb, Kb, Vtb);
  attn_kernel<<<dim3(2048), 256, 0, stream>>>(Qb, Kb, Vtb, Ob);
  gemm_out<<<dim3(64, 8), 256, 0, stream>>>(Ob, wot, bo, (float*)d_out);
}

// Round 7
// 288.466 us; speedup vs baseline: 1.1656x; 1.1656x over previous
//
#include <hip/hip_runtime.h>
#include <hip/hip_bf16.h>
#include <cstdint>

// MultiHeadSelfAttention: B=4, N=2048, C=1024, H=16, D=64
// R13 8-phase: 87.5us (no change). R14 cohort map: 96.8 (worse).
// R15/16 A-only LDS + direct-B: 132.4 (much worse — B loads 16B/lane at 2KB
//  stride = ~8x transaction amplification; coalescing != L2 residency).
// R17 (delta from R16):
//  - gemm_qkv: REVERT to R12-exact (best measured: 88.6us / 582 TF; 2-phase
//    128x128, both A+B via global_load_lds, BK=64).
//  - attn: V double-buffer (vf0/vf1 parity) so V(i+1) loads 2 sub-iters
//    before its PV use, symmetric with kf prefetch. +16 VGPR.

typedef __attribute__((ext_vector_type(8))) short short8;    // 8 bf16
typedef __attribute__((ext_vector_type(4))) float floatx4;

#if __has_builtin(__builtin_amdgcn_exp2f)
#define EXP2F(x) __builtin_amdgcn_exp2f(x)
#else
#define EXP2F(x) __expf((x) * 0.6931471805599453f)
#endif

__device__ __forceinline__ unsigned short f2bf(float f) {
  unsigned u = __float_as_uint(f);
  unsigned r = u + 0x7fffu + ((u >> 16) & 1u);   // RNE
  return (unsigned short)(r >> 16);
}

__device__ __forceinline__ void async16(const void* g, void* l) {
  __builtin_amdgcn_global_load_lds(
      (__attribute__((address_space(1))) void*)(void*)(uintptr_t)g,
      (__attribute__((address_space(3))) void*)l, 16, 0, 0);
}

// ------------------------------------------- prep: x cvt + 4x W^T (merged)
__global__ __launch_bounds__(256) void prep_kernel(
    const float* __restrict__ x, unsigned short* __restrict__ xb,
    const float* __restrict__ W0, const float* __restrict__ W1,
    const float* __restrict__ W2, const float* __restrict__ W3,
    unsigned short* __restrict__ T0, unsigned short* __restrict__ T1,
    unsigned short* __restrict__ T2, unsigned short* __restrict__ T3) {
  const int tid = threadIdx.x;
  int blk = blockIdx.x;
  if (blk < 8192) {               // ---- x f32 -> bf16
    int i = (blk * 256 + tid) * 4;
    float4 v = *(const float4*)(x + i);
    ushort4 o;
    o.x = f2bf(v.x); o.y = f2bf(v.y); o.z = f2bf(v.z); o.w = f2bf(v.w);
    *(ushort4*)(xb + i) = o;
  } else {                        // ---- W transpose+convert, 32x32 tiles
    int t = blk - 8192;
    int z = t >> 10, tile = t & 1023;
    const float* W = z == 0 ? W0 : z == 1 ? W1 : z == 2 ? W2 : W3;
    unsigned short* T = z == 0 ? T0 : z == 1 ? T1 : z == 2 ? T2 : T3;
    __shared__ float tb[32][33];
    int tx = tid & 31, ty = tid >> 5;            // 32 x 8
    int bx = (tile & 31) * 32, by = (tile >> 5) * 32;
#pragma unroll
    for (int i = 0; i < 4; ++i)
      tb[ty + i * 8][tx] = W[(size_t)(by + ty + i * 8) * 1024 + bx + tx];
    __syncthreads();
#pragma unroll
    for (int i = 0; i < 4; ++i)
      T[(size_t)(bx + ty + i * 8) * 1024 + by + tx] = f2bf(tb[tx][ty + i * 8]);
  }
}

// ------------------------------------------- fused QKV projection (M x 3072)
// R12-exact: BK=64, As/Bs = [half][row][32] (16KB each). Direct-scatter epi.
__global__ __launch_bounds__(256) void gemm_qkv(
    const unsigned short* __restrict__ A, const unsigned short* __restrict__ BT,
    const float* __restrict__ bq, const float* __restrict__ bk,
    const float* __restrict__ bv,
    unsigned short* __restrict__ Qo, unsigned short* __restrict__ Ko,
    unsigned short* __restrict__ Vo) {
  constexpr int Kd = 1024;
  __shared__ unsigned short As[2 * 128 * 32];
  __shared__ unsigned short Bs[2 * 128 * 32];
  const int tid = threadIdx.x;
  const int wave = tid >> 6, lane = tid & 63;
  const int quad = lane >> 4, l16 = lane & 15;
  const int wm = (wave & 1) * 64, wn = (wave >> 1) * 64;
  const int m0 = blockIdx.x * 128, n0 = blockIdx.y * 128;
  const int mid = blockIdx.y >> 3;                 // 0=Q 1=K 2=V
  const float* bias = mid == 0 ? bq : mid == 1 ? bk : bv;
  const float scale = mid == 0 ? 0.180336880021082f : 1.0f;  // Q: 0.125*log2(e)

  floatx4 acc[4][4] = {};
  const unsigned short* Ag = A + (size_t)m0 * Kd;
  const unsigned short* Bg = BT + (size_t)n0 * Kd;

  for (int k0 = 0; k0 < Kd; k0 += 64) {
    __syncthreads();
#pragma unroll
    for (int p = 0; p < 4; ++p) {
      int c = (wave * 4 + p) * 64 + lane;
      int h = c >> 9, row = (c >> 2) & 127, kp = c & 3;
      async16(Ag + (size_t)row * Kd + k0 + h * 32 + kp * 8, (char*)As + (size_t)(wave * 4 + p) * 1024);
      async16(Bg + (size_t)row * Kd + k0 + h * 32 + kp * 8, (char*)Bs + (size_t)(wave * 4 + p) * 1024);
    }
    __syncthreads();
#pragma unroll
    for (int ks = 0; ks < 2; ++ks) {
      short8 a[4], b[4];
#pragma unroll
      for (int i = 0; i < 4; ++i) {
        a[i] = *(const short8*)(As + ks * 4096 + (wm + i * 16 + l16) * 32 + quad * 8);
        b[i] = *(const short8*)(Bs + ks * 4096 + (wn + i * 16 + l16) * 32 + quad * 8);
      }
#pragma unroll
      for (int i = 0; i < 4; ++i)
#pragma unroll
        for (int j = 0; j < 4; ++j)
          acc[i][j] = __builtin_amdgcn_mfma_f32_16x16x32_bf16(a[i], b[j], acc[i][j], 0, 0, 0);
    }
  }

#pragma unroll
  for (int j = 0; j < 4; ++j) {
    int gcol = n0 + wn + j * 16 + l16;
    int cn = gcol & 1023;
    float bb = bias[cn];
    int h = cn >> 6, d = cn & 63;
#pragma unroll
    for (int i = 0; i < 4; ++i) {
      int rbase = m0 + wm + i * 16 + quad * 4;
#pragma unroll
      for (int r = 0; r < 4; ++r) {
        int row = rbase + r;
        unsigned short hv = f2bf((acc[i][j][r] + bb) * scale);
        int bi = row >> 11, ni = row & 2047;
        size_t bh = (size_t)bi * 16 + h;
        if (mid == 2) {   // V^T B-frag, key order interleaved: pos=(jk&15)*2|(jk>>4)
          int nt = d >> 4, vl = d & 15;
          int kq = ni >> 5, jk = ni & 31;
          int pos = ((jk & 15) << 1) | (jk >> 4);
          Vo[((bh * 64 + kq) * 4 + nt) * 512 + (pos >> 3) * 128 + vl * 8 + (pos & 7)] = hv;
        } else {          // Q/K frag: block (bh*128 + tok16)*2 + kk
          int kfg = ni >> 4, tl = ni & 15;
          int kk = d >> 5, dq = (d & 31) >> 3, dj = d & 7;
          unsigned short* outp = mid == 0 ? Qo : Ko;
          outp[((bh * 128 + kfg) * 2 + kk) * 512 + dq * 128 + tl * 8 + dj] = hv;
        }
      }
    }
  }
}

// --------------------------------------------------------------- attention
// Block: 4 waves = 2 q-groups (32 rows) x 2 key-halves (32 kt each).
// Grid 2048. No barriers in main loop. P parity double-buffer + K-frag
// prefetch (R10) + setprio (R12) + V double-buffer (R17: vf0/vf1 parity,
// V(i+1) loaded 2 sub-iters before its PV use).
__global__ __launch_bounds__(256, 3) void attn_kernel(
    const unsigned short* __restrict__ Qs, const unsigned short* __restrict__ Ksw,
    const unsigned short* __restrict__ Vsw, unsigned short* __restrict__ O) {
  __shared__ __align__(16) char smem[20480];

  const int tid = threadIdx.x, wave = tid >> 6, lane = tid & 63;
  const int quad = lane >> 4, l16 = lane & 15;
  const int wk = wave & 1, wqi = wave >> 1;
  int blk = blockIdx.x;
  int xcd = blk & 7, slot = blk >> 3;
  int bh = (slot & 7) * 8 + xcd, qb = slot >> 3;   // qb: 0..31 (64-row blocks)

  unsigned short* Pw0 = (unsigned short*)(smem + wave * 5120);
  unsigned short* Pw1 = (unsigned short*)(smem + wave * 5120 + 2560);

  // Q A-frags (2 row-tiles x 2 k-halves)
  short8 aq[2][2];
#pragma unroll
  for (int rt = 0; rt < 2; ++rt)
#pragma unroll
    for (int kk = 0; kk < 2; ++kk)
      aq[rt][kk] = *(const short8*)(Qs +
          (((size_t)bh * 128 + qb * 4 + wqi * 2 + rt) * 2 + kk) * 512 + lane * 8);

  short8 ones;
#pragma unroll
  for (int i = 0; i < 8; ++i) ones[i] = (short)0x3F80;   // bf16 1.0

  const float MSUB = 17.3123404906675611f;   // 12*log2(e); scores in log2 units
  floatx4 mneg;
#pragma unroll
  for (int i = 0; i < 4; ++i) mneg[i] = -MSUB;

  floatx4 acc_o[2][4] = {};
  floatx4 acc_l[2] = {};

  const unsigned short* kptr0 = Ksw + (size_t)bh * 128 * 2 * 512 + (size_t)wk * 32 * 2048;
  const unsigned short* vptr0 = Vsw + (size_t)bh * 64 * 4 * 512 + (size_t)wk * 32 * 2048;

  short8 kf0[2][2], kf1[2][2], vf0[4], vf1[4];
  floatx4 sacc[2][2];

#define LOAD_KF(dst, KT)                                                          \
  {                                                                               \
    _Pragma("unroll") for (int ct = 0; ct < 2; ++ct)                              \
        _Pragma("unroll") for (int kk = 0; kk < 2; ++kk)                          \
            dst[ct][kk] = *(const short8*)(kptr0 + (size_t)(KT)*2048 +            \
                                           (ct * 2 + kk) * 512 + lane * 8);       \
  }
#define LOAD_VF(dst, KT)                                                          \
  {                                                                               \
    _Pragma("unroll") for (int nt = 0; nt < 4; ++nt)                              \
        dst[nt] = *(const short8*)(vptr0 + (size_t)(KT)*2048 + nt * 512 + lane * 8); \
  }
#define QK_BLOCK(KF)                                                              \
  {                                                                               \
    __builtin_amdgcn_s_setprio(1);                                                \
    _Pragma("unroll") for (int rt = 0; rt < 2; ++rt)                              \
        _Pragma("unroll") for (int ct = 0; ct < 2; ++ct) {                        \
      sacc[rt][ct] = __builtin_amdgcn_mfma_f32_16x16x32_bf16(aq[rt][0], KF[ct][0], mneg, 0, 0, 0); \
      sacc[rt][ct] = __builtin_amdgcn_mfma_f32_16x16x32_bf16(aq[rt][1], KF[ct][1], sacc[rt][ct], 0, 0, 0); \
    }                                                                             \
    __builtin_amdgcn_s_setprio(0);                                                \
  }
#define EXP_WRITE(PBUF)                                                           \
  {                                                                               \
    _Pragma("unroll") for (int rt = 0; rt < 2; ++rt)                              \
        _Pragma("unroll") for (int r = 0; r < 4; ++r) {                           \
      float pe = EXP2F(sacc[rt][0][r]);                                           \
      float po = EXP2F(sacc[rt][1][r]);                                           \
      unsigned pk = __builtin_amdgcn_perm(__float_as_uint(po), __float_as_uint(pe), 0x07060302u); \
      ((unsigned*)((PBUF) + (rt * 16 + quad * 4 + r) * 40))[l16] = pk;            \
    }                                                                             \
  }
#define PV_BLOCK(PBUF, VF)                                                        \
  {                                                                               \
    __builtin_amdgcn_s_setprio(1);                                                \
    _Pragma("unroll") for (int rt = 0; rt < 2; ++rt) {                            \
      short8 ap = *(const short8*)((PBUF) + (rt * 16 + l16) * 40 + quad * 8);     \
      acc_l[rt] = __builtin_amdgcn_mfma_f32_16x16x32_bf16(ap, ones, acc_l[rt], 0, 0, 0); \
      _Pragma("unroll") for (int nt = 0; nt < 4; ++nt)                            \
          acc_o[rt][nt] = __builtin_amdgcn_mfma_f32_16x16x32_bf16(ap, VF[nt], acc_o[rt][nt], 0, 0, 0); \
    }                                                                             \
    __builtin_amdgcn_s_setprio(0);                                                \
  }

  // ---- prologue: K(0),K(1),V(0),V(1); QK(0); P(0)->Pw0
  LOAD_KF(kf0, 0);
  LOAD_KF(kf1, 1);
  LOAD_VF(vf0, 0);
  LOAD_VF(vf1, 1);
  QK_BLOCK(kf0);
  EXP_WRITE(Pw0);

  // ---- main: V(j) lives in vf[j&1]; P(j) in Pw[j&1]; K(j) in kf[j&1].
  // sub-iter i: prefetch K(i+1); QK(i); PV(i-1) w/ vf[(i-1)&1];
  //             prefetch V(i+1) into the vf buffer PV just freed; EXP(i).
  for (int it = 0; it < 15; ++it) {
    const int i1 = 2 * it + 1, i2 = 2 * it + 2;
    // odd sub-iter (i1)
    LOAD_KF(kf0, i1 + 1);
    QK_BLOCK(kf1);
    PV_BLOCK(Pw0, vf0);       // PV(i1-1), V(i1-1) in vf0
    LOAD_VF(vf0, i1 + 1);     // V(i1+1) -> vf0 (used at sub-iter i1+2)
    EXP_WRITE(Pw1);
    // even sub-iter (i2)
    LOAD_KF(kf1, i2 + 1);
    QK_BLOCK(kf0);
    PV_BLOCK(Pw1, vf1);       // PV(i2-1), V(i2-1) in vf1
    LOAD_VF(vf1, i2 + 1);     // V(i2+1) -> vf1
    EXP_WRITE(Pw0);
  }
  // ---- tail: i = 31 (V(30) in vf0, V(31) in vf1 — already loaded)
  QK_BLOCK(kf1);
  PV_BLOCK(Pw0, vf0);         // PV(30)
  EXP_WRITE(Pw1);
  PV_BLOCK(Pw1, vf1);         // PV(31)

#undef LOAD_KF
#undef LOAD_VF
#undef QK_BLOCK
#undef EXP_WRITE
#undef PV_BLOCK

  // ---- combine key halves, normalize, store
  float* buf = (float*)smem + wqi * 2176;          // 32 x 68 f32
  float* lbuf = (float*)(smem + 17408);            // 64 f32
  __syncthreads();
  if (wk == 1) {
#pragma unroll
    for (int rt = 0; rt < 2; ++rt)
#pragma unroll
      for (int r = 0; r < 4; ++r) {
        int row = rt * 16 + quad * 4 + r;
#pragma unroll
        for (int nt = 0; nt < 4; ++nt)
          buf[row * 68 + nt * 16 + l16] = acc_o[rt][nt][r];
        if (l16 == 0) lbuf[wqi * 32 + row] = acc_l[rt][r];
      }
  }
  __syncthreads();
  if (wk == 0) {
    const int b = bh >> 4, h = bh & 15;
#pragma unroll
    for (int rt = 0; rt < 2; ++rt)
#pragma unroll
      for (int r = 0; r < 4; ++r) {
        int row = rt * 16 + quad * 4 + r;
        float linv = 1.0f / (acc_l[rt][r] + lbuf[wqi * 32 + row]);
        int grow = qb * 64 + wqi * 32 + row;
#pragma unroll
        for (int nt = 0; nt < 4; ++nt) {
          float v = (acc_o[rt][nt][r] + buf[row * 68 + nt * 16 + l16]) * linv;
          O[((size_t)b * 2048 + grow) * 1024 + h * 64 + nt * 16 + l16] = f2bf(v);
        }
      }
  }
}

// ------------------------------------------------------------- output GEMM
// BK=64, same staging as R10.
__global__ __launch_bounds__(256) void gemm_out(
    const unsigned short* __restrict__ A, const unsigned short* __restrict__ BT,
    const float* __restrict__ bias, float* __restrict__ of) {
  constexpr int Kd = 1024;
  __shared__ unsigned short As[2 * 128 * 32];
  __shared__ unsigned short Bs[2 * 128 * 32];
  const int tid = threadIdx.x;
  const int wave = tid >> 6, lane = tid & 63;
  const int quad = lane >> 4, l16 = lane & 15;
  const int wm = (wave & 1) * 64, wn = (wave >> 1) * 64;
  const int m0 = blockIdx.x * 128, n0 = blockIdx.y * 128;

  floatx4 acc[4][4] = {};
  const unsigned short* Ag = A + (size_t)m0 * Kd;
  const unsigned short* Bg = BT + (size_t)n0 * Kd;

  for (int k0 = 0; k0 < Kd; k0 += 64) {
    __syncthreads();
#pragma unroll
    for (int p = 0; p < 4; ++p) {
      int c = (wave * 4 + p) * 64 + lane;
      int h = c >> 9, row = (c >> 2) & 127, kp = c & 3;
      async16(Ag + (size_t)row * Kd + k0 + h * 32 + kp * 8, (char*)As + (size_t)(wave * 4 + p) * 1024);
      async16(Bg + (size_t)row * Kd + k0 + h * 32 + kp * 8, (char*)Bs + (size_t)(wave * 4 + p) * 1024);
    }
    __syncthreads();
#pragma unroll
    for (int ks = 0; ks < 2; ++ks) {
      short8 a[4], b[4];
#pragma unroll
      for (int i = 0; i < 4; ++i) {
        a[i] = *(const short8*)(As + ks * 4096 + (wm + i * 16 + l16) * 32 + quad * 8);
        b[i] = *(const short8*)(Bs + ks * 4096 + (wn + i * 16 + l16) * 32 + quad * 8);
      }
#pragma unroll
      for (int i = 0; i < 4; ++i)
#pragma unroll
        for (int j = 0; j < 4; ++j)
          acc[i][j] = __builtin_amdgcn_mfma_f32_16x16x32_bf16(a[i], b[j], acc[i][j], 0, 0, 0);
    }
  }

#pragma unroll
  for (int j = 0; j < 4; ++j) {
    int col = n0 + wn + j * 16 + l16;
    float bb = bias[col];
#pragma unroll
    for (int i = 0; i < 4; ++i) {
      int rbase = m0 + wm + i * 16 + quad * 4;
#pragma unroll
      for (int r = 0; r < 4; ++r)
        of[(size_t)(rbase + r) * 1024 + col] = acc[i][j][r] + bb;
    }
  }
}

// ---------------------------------------------------------------- launch
extern "C" void kernel_launch(void* const* d_in, const int* in_sizes, int n_in,
                              void* d_out, int out_size, void* d_ws, size_t ws_size,
                              hipStream_t stream) {
  const float* x  = (const float*)d_in[0];
  const float* Wq = (const float*)d_in[1];
  const float* bq = (const float*)d_in[2];
  const float* Wk = (const float*)d_in[3];
  const float* bk = (const float*)d_in[4];
  const float* Wv = (const float*)d_in[5];
  const float* bv = (const float*)d_in[6];
  const float* Wo = (const float*)d_in[7];
  const float* bo = (const float*)d_in[8];

  char* ws = (char*)d_ws;
  unsigned short* xb  = (unsigned short*)(ws);                 // 16 MiB
  unsigned short* wqt = (unsigned short*)(ws + (16u << 20));   // 2 MiB each, contiguous
  unsigned short* wkt = (unsigned short*)(ws + (18u << 20));
  unsigned short* wvt = (unsigned short*)(ws + (20u << 20));
  unsigned short* wot = (unsigned short*)(ws + (22u << 20));
  unsigned short* Qb  = (unsigned short*)(ws + (24u << 20));   // 16 MiB each
  unsigned short* Kb  = (unsigned short*)(ws + (40u << 20));
  unsigned short* Vtb = (unsigned short*)(ws + (56u << 20));
  unsigned short* Ob  = (unsigned short*)(ws + (72u << 20));   // total 88 MiB

  prep_kernel<<<dim3(12288), 256, 0, stream>>>(x, xb, Wq, Wk, Wv, Wo, wqt, wkt, wvt, wot);
  gemm_qkv<<<dim3(64, 24), 256, 0, stream>>>(xb, wqt, bq, bk, bv, Qb, Kb, Vtb);
  attn_kernel<<<dim3(2048), 256, 0, stream>>>(Qb, Kb, Vtb, Ob);
  gemm_out<<<dim3(64, 8), 256, 0, stream>>>(Ob, wot, bo, (float*)d_out);
}

// Round 8
// 277.275 us; speedup vs baseline: 1.2126x; 1.0404x over previous
//
#include <hip/hip_runtime.h>
#include <hip/hip_bf16.h>
#include <cstdint>

// MultiHeadSelfAttention: B=4, N=2048, C=1024, H=16, D=64
// R13 8-phase: 87.5 (null). R14 cohort: 96.8 (worse). R15/16 direct-B: 132.4
//  (uncoalesced 16B/lane @2KB stride). R17: revert gemm to R12-exact (88.4
//  reproduced); attn V-dbuf (neutral-to-tiny-positive, kept).
// R18 (delta from R17): gemm_qkv EPILOGUE ONLY — the one component identical
//  across all three ~88us K-loop variants, never ablated. Old: 64 scalar 2B
//  scattered stores/thread (~8 segments per wave-store, WRITE 48MB vs 37.7
//  payload). New: scatter to LDS (As/Bs merged 32KB, dead after K-loop; each
//  head's output chunk is a contiguous 16KB region, offsets bijective) then
//  8x coalesced 1KB global_store_dwordx4/thread. K-loop untouched.

typedef __attribute__((ext_vector_type(8))) short short8;    // 8 bf16
typedef __attribute__((ext_vector_type(4))) float floatx4;

#if __has_builtin(__builtin_amdgcn_exp2f)
#define EXP2F(x) __builtin_amdgcn_exp2f(x)
#else
#define EXP2F(x) __expf((x) * 0.6931471805599453f)
#endif

__device__ __forceinline__ unsigned short f2bf(float f) {
  unsigned u = __float_as_uint(f);
  unsigned r = u + 0x7fffu + ((u >> 16) & 1u);   // RNE
  return (unsigned short)(r >> 16);
}

__device__ __forceinline__ void async16(const void* g, void* l) {
  __builtin_amdgcn_global_load_lds(
      (__attribute__((address_space(1))) void*)(void*)(uintptr_t)g,
      (__attribute__((address_space(3))) void*)l, 16, 0, 0);
}

// ------------------------------------------- prep: x cvt + 4x W^T (merged)
__global__ __launch_bounds__(256) void prep_kernel(
    const float* __restrict__ x, unsigned short* __restrict__ xb,
    const float* __restrict__ W0, const float* __restrict__ W1,
    const float* __restrict__ W2, const float* __restrict__ W3,
    unsigned short* __restrict__ T0, unsigned short* __restrict__ T1,
    unsigned short* __restrict__ T2, unsigned short* __restrict__ T3) {
  const int tid = threadIdx.x;
  int blk = blockIdx.x;
  if (blk < 8192) {               // ---- x f32 -> bf16
    int i = (blk * 256 + tid) * 4;
    float4 v = *(const float4*)(x + i);
    ushort4 o;
    o.x = f2bf(v.x); o.y = f2bf(v.y); o.z = f2bf(v.z); o.w = f2bf(v.w);
    *(ushort4*)(xb + i) = o;
  } else {                        // ---- W transpose+convert, 32x32 tiles
    int t = blk - 8192;
    int z = t >> 10, tile = t & 1023;
    const float* W = z == 0 ? W0 : z == 1 ? W1 : z == 2 ? W2 : W3;
    unsigned short* T = z == 0 ? T0 : z == 1 ? T1 : z == 2 ? T2 : T3;
    __shared__ float tb[32][33];
    int tx = tid & 31, ty = tid >> 5;            // 32 x 8
    int bx = (tile & 31) * 32, by = (tile >> 5) * 32;
#pragma unroll
    for (int i = 0; i < 4; ++i)
      tb[ty + i * 8][tx] = W[(size_t)(by + ty + i * 8) * 1024 + bx + tx];
    __syncthreads();
#pragma unroll
    for (int i = 0; i < 4; ++i)
      T[(size_t)(bx + ty + i * 8) * 1024 + by + tx] = f2bf(tb[tx][ty + i * 8]);
  }
}

// ------------------------------------------- fused QKV projection (M x 3072)
// K-loop R12-exact: BK=64, As/Bs = [half][row][32] (16KB each, merged in SH).
// R18 epilogue: LDS scatter + coalesced copy-out.
__global__ __launch_bounds__(256) void gemm_qkv(
    const unsigned short* __restrict__ A, const unsigned short* __restrict__ BT,
    const float* __restrict__ bq, const float* __restrict__ bk,
    const float* __restrict__ bv,
    unsigned short* __restrict__ Qo, unsigned short* __restrict__ Ko,
    unsigned short* __restrict__ Vo) {
  constexpr int Kd = 1024;
  __shared__ unsigned short SH[16384];            // As 16KB | Bs 16KB
  unsigned short* const As = SH;
  unsigned short* const Bs = SH + 8192;
  const int tid = threadIdx.x;
  const int wave = tid >> 6, lane = tid & 63;
  const int quad = lane >> 4, l16 = lane & 15;
  const int wm = (wave & 1) * 64, wn = (wave >> 1) * 64;
  const int m0 = blockIdx.x * 128, n0 = blockIdx.y * 128;
  const int mid = blockIdx.y >> 3;                 // 0=Q 1=K 2=V
  const float* bias = mid == 0 ? bq : mid == 1 ? bk : bv;
  const float scale = mid == 0 ? 0.180336880021082f : 1.0f;  // Q: 0.125*log2(e)

  floatx4 acc[4][4] = {};
  const unsigned short* Ag = A + (size_t)m0 * Kd;
  const unsigned short* Bg = BT + (size_t)n0 * Kd;

  for (int k0 = 0; k0 < Kd; k0 += 64) {
    __syncthreads();
#pragma unroll
    for (int p = 0; p < 4; ++p) {
      int c = (wave * 4 + p) * 64 + lane;
      int h = c >> 9, row = (c >> 2) & 127, kp = c & 3;
      async16(Ag + (size_t)row * Kd + k0 + h * 32 + kp * 8, (char*)As + (size_t)(wave * 4 + p) * 1024);
      async16(Bg + (size_t)row * Kd + k0 + h * 32 + kp * 8, (char*)Bs + (size_t)(wave * 4 + p) * 1024);
    }
    __syncthreads();
#pragma unroll
    for (int ks = 0; ks < 2; ++ks) {
      short8 a[4], b[4];
#pragma unroll
      for (int i = 0; i < 4; ++i) {
        a[i] = *(const short8*)(As + ks * 4096 + (wm + i * 16 + l16) * 32 + quad * 8);
        b[i] = *(const short8*)(Bs + ks * 4096 + (wn + i * 16 + l16) * 32 + quad * 8);
      }
#pragma unroll
      for (int i = 0; i < 4; ++i)
#pragma unroll
        for (int j = 0; j < 4; ++j)
          acc[i][j] = __builtin_amdgcn_mfma_f32_16x16x32_bf16(a[i], b[j], acc[i][j], 0, 0, 0);
    }
  }

  // ---- R18 epilogue: permuted scatter into SH (chunk = head parity), then
  //      coalesced copy-out (2 heads x 16KB contiguous global chunks).
  __syncthreads();                                 // K-loop LDS reads done
#pragma unroll
  for (int j = 0; j < 4; ++j) {
    int gcol = n0 + wn + j * 16 + l16;
    int cn = gcol & 1023;
    float bb = bias[cn];
    int h = cn >> 6, d = cn & 63;
    int c = h & 1;                                 // n0%128==0 -> hbase even
#pragma unroll
    for (int i = 0; i < 4; ++i) {
      int rbase = m0 + wm + i * 16 + quad * 4;
#pragma unroll
      for (int r = 0; r < 4; ++r) {
        int row = rbase + r;
        unsigned short hv = f2bf((acc[i][j][r] + bb) * scale);
        int ni = row & 2047;
        int off;
        if (mid == 2) {   // V^T frag: ((kq-kq0)*4+nt)*512 + (pos>>3)*128+vl*8+(pos&7)
          int nt = d >> 4, vl = d & 15;
          int kq2 = (ni >> 5) & 3;                 // kq0 multiple of 4
          int jk = ni & 31;
          int pos = ((jk & 15) << 1) | (jk >> 4);
          off = (kq2 * 4 + nt) * 512 + (pos >> 3) * 128 + vl * 8 + (pos & 7);
        } else {          // Q/K frag: ((kfg-kfg0)*2+kk)*512 + dq*128+tl*8+dj
          int kfg2 = (ni >> 4) & 7;                // kfg0 multiple of 8
          int tl = ni & 15;
          int kk = d >> 5, dq = (d & 31) >> 3, dj = d & 7;
          off = (kfg2 * 2 + kk) * 512 + dq * 128 + tl * 8 + dj;
        }
        SH[c * 8192 + off] = hv;
      }
    }
  }
  __syncthreads();
  {
    int bi = m0 >> 11;                             // all 128 rows share bi
    int hbase = (n0 & 1023) >> 6;                  // first head of this tile
    unsigned short* outp = mid == 0 ? Qo : mid == 1 ? Ko : Vo;
    int kq0 = (m0 & 2047) >> 5, kfg0 = (m0 & 2047) >> 4;
#pragma unroll
    for (int it = 0; it < 8; ++it) {
      int o = it * 2048 + tid * 8;                 // ushort offset in SH
      int c = o >> 13, oo = o & 8191;
      size_t bh = (size_t)bi * 16 + hbase + c;
      size_t base = (mid == 2) ? ((bh * 64 + kq0) * 4) * 512
                               : ((bh * 128 + kfg0) * 2) * 512;
      *(short8*)(outp + base + oo) = *(const short8*)(SH + o);
    }
  }
}

// --------------------------------------------------------------- attention
// Block: 4 waves = 2 q-groups (32 rows) x 2 key-halves (32 kt each).
// Grid 2048. No barriers in main loop. P parity double-buffer + K-frag
// prefetch (R10) + setprio (R12) + V double-buffer (R17).
__global__ __launch_bounds__(256, 3) void attn_kernel(
    const unsigned short* __restrict__ Qs, const unsigned short* __restrict__ Ksw,
    const unsigned short* __restrict__ Vsw, unsigned short* __restrict__ O) {
  __shared__ __align__(16) char smem[20480];

  const int tid = threadIdx.x, wave = tid >> 6, lane = tid & 63;
  const int quad = lane >> 4, l16 = lane & 15;
  const int wk = wave & 1, wqi = wave >> 1;
  int blk = blockIdx.x;
  int xcd = blk & 7, slot = blk >> 3;
  int bh = (slot & 7) * 8 + xcd, qb = slot >> 3;   // qb: 0..31 (64-row blocks)

  unsigned short* Pw0 = (unsigned short*)(smem + wave * 5120);
  unsigned short* Pw1 = (unsigned short*)(smem + wave * 5120 + 2560);

  // Q A-frags (2 row-tiles x 2 k-halves)
  short8 aq[2][2];
#pragma unroll
  for (int rt = 0; rt < 2; ++rt)
#pragma unroll
    for (int kk = 0; kk < 2; ++kk)
      aq[rt][kk] = *(const short8*)(Qs +
          (((size_t)bh * 128 + qb * 4 + wqi * 2 + rt) * 2 + kk) * 512 + lane * 8);

  short8 ones;
#pragma unroll
  for (int i = 0; i < 8; ++i) ones[i] = (short)0x3F80;   // bf16 1.0

  const float MSUB = 17.3123404906675611f;   // 12*log2(e); scores in log2 units
  floatx4 mneg;
#pragma unroll
  for (int i = 0; i < 4; ++i) mneg[i] = -MSUB;

  floatx4 acc_o[2][4] = {};
  floatx4 acc_l[2] = {};

  const unsigned short* kptr0 = Ksw + (size_t)bh * 128 * 2 * 512 + (size_t)wk * 32 * 2048;
  const unsigned short* vptr0 = Vsw + (size_t)bh * 64 * 4 * 512 + (size_t)wk * 32 * 2048;

  short8 kf0[2][2], kf1[2][2], vf0[4], vf1[4];
  floatx4 sacc[2][2];

#define LOAD_KF(dst, KT)                                                          \
  {                                                                               \
    _Pragma("unroll") for (int ct = 0; ct < 2; ++ct)                              \
        _Pragma("unroll") for (int kk = 0; kk < 2; ++kk)                          \
            dst[ct][kk] = *(const short8*)(kptr0 + (size_t)(KT)*2048 +            \
                                           (ct * 2 + kk) * 512 + lane * 8);       \
  }
#define LOAD_VF(dst, KT)                                                          \
  {                                                                               \
    _Pragma("unroll") for (int nt = 0; nt < 4; ++nt)                              \
        dst[nt] = *(const short8*)(vptr0 + (size_t)(KT)*2048 + nt * 512 + lane * 8); \
  }
#define QK_BLOCK(KF)                                                              \
  {                                                                               \
    __builtin_amdgcn_s_setprio(1);                                                \
    _Pragma("unroll") for (int rt = 0; rt < 2; ++rt)                              \
        _Pragma("unroll") for (int ct = 0; ct < 2; ++ct) {                        \
      sacc[rt][ct] = __builtin_amdgcn_mfma_f32_16x16x32_bf16(aq[rt][0], KF[ct][0], mneg, 0, 0, 0); \
      sacc[rt][ct] = __builtin_amdgcn_mfma_f32_16x16x32_bf16(aq[rt][1], KF[ct][1], sacc[rt][ct], 0, 0, 0); \
    }                                                                             \
    __builtin_amdgcn_s_setprio(0);                                                \
  }
#define EXP_WRITE(PBUF)                                                           \
  {                                                                               \
    _Pragma("unroll") for (int rt = 0; rt < 2; ++rt)                              \
        _Pragma("unroll") for (int r = 0; r < 4; ++r) {                           \
      float pe = EXP2F(sacc[rt][0][r]);                                           \
      float po = EXP2F(sacc[rt][1][r]);                                           \
      unsigned pk = __builtin_amdgcn_perm(__float_as_uint(po), __float_as_uint(pe), 0x07060302u); \
      ((unsigned*)((PBUF) + (rt * 16 + quad * 4 + r) * 40))[l16] = pk;            \
    }                                                                             \
  }
#define PV_BLOCK(PBUF, VF)                                                        \
  {                                                                               \
    __builtin_amdgcn_s_setprio(1);                                                \
    _Pragma("unroll") for (int rt = 0; rt < 2; ++rt) {                            \
      short8 ap = *(const short8*)((PBUF) + (rt * 16 + l16) * 40 + quad * 8);     \
      acc_l[rt] = __builtin_amdgcn_mfma_f32_16x16x32_bf16(ap, ones, acc_l[rt], 0, 0, 0); \
      _Pragma("unroll") for (int nt = 0; nt < 4; ++nt)                            \
          acc_o[rt][nt] = __builtin_amdgcn_mfma_f32_16x16x32_bf16(ap, VF[nt], acc_o[rt][nt], 0, 0, 0); \
    }                                                                             \
    __builtin_amdgcn_s_setprio(0);                                                \
  }

  // ---- prologue: K(0),K(1),V(0),V(1); QK(0); P(0)->Pw0
  LOAD_KF(kf0, 0);
  LOAD_KF(kf1, 1);
  LOAD_VF(vf0, 0);
  LOAD_VF(vf1, 1);
  QK_BLOCK(kf0);
  EXP_WRITE(Pw0);

  // ---- main: V(j) in vf[j&1]; P(j) in Pw[j&1]; K(j) in kf[j&1].
  for (int it = 0; it < 15; ++it) {
    const int i1 = 2 * it + 1, i2 = 2 * it + 2;
    // odd sub-iter (i1)
    LOAD_KF(kf0, i1 + 1);
    QK_BLOCK(kf1);
    PV_BLOCK(Pw0, vf0);       // PV(i1-1), V(i1-1) in vf0
    LOAD_VF(vf0, i1 + 1);     // V(i1+1) -> vf0
    EXP_WRITE(Pw1);
    // even sub-iter (i2)
    LOAD_KF(kf1, i2 + 1);
    QK_BLOCK(kf0);
    PV_BLOCK(Pw1, vf1);       // PV(i2-1), V(i2-1) in vf1
    LOAD_VF(vf1, i2 + 1);     // V(i2+1) -> vf1
    EXP_WRITE(Pw0);
  }
  // ---- tail: i = 31 (V(30) in vf0, V(31) in vf1 — already loaded)
  QK_BLOCK(kf1);
  PV_BLOCK(Pw0, vf0);         // PV(30)
  EXP_WRITE(Pw1);
  PV_BLOCK(Pw1, vf1);         // PV(31)

#undef LOAD_KF
#undef LOAD_VF
#undef QK_BLOCK
#undef EXP_WRITE
#undef PV_BLOCK

  // ---- combine key halves, normalize, store
  float* buf = (float*)smem + wqi * 2176;          // 32 x 68 f32
  float* lbuf = (float*)(smem + 17408);            // 64 f32
  __syncthreads();
  if (wk == 1) {
#pragma unroll
    for (int rt = 0; rt < 2; ++rt)
#pragma unroll
      for (int r = 0; r < 4; ++r) {
        int row = rt * 16 + quad * 4 + r;
#pragma unroll
        for (int nt = 0; nt < 4; ++nt)
          buf[row * 68 + nt * 16 + l16] = acc_o[rt][nt][r];
        if (l16 == 0) lbuf[wqi * 32 + row] = acc_l[rt][r];
      }
  }
  __syncthreads();
  if (wk == 0) {
    const int b = bh >> 4, h = bh & 15;
#pragma unroll
    for (int rt = 0; rt < 2; ++rt)
#pragma unroll
      for (int r = 0; r < 4; ++r) {
        int row = rt * 16 + quad * 4 + r;
        float linv = 1.0f / (acc_l[rt][r] + lbuf[wqi * 32 + row]);
        int grow = qb * 64 + wqi * 32 + row;
#pragma unroll
        for (int nt = 0; nt < 4; ++nt) {
          float v = (acc_o[rt][nt][r] + buf[row * 68 + nt * 16 + l16]) * linv;
          O[((size_t)b * 2048 + grow) * 1024 + h * 64 + nt * 16 + l16] = f2bf(v);
        }
      }
  }
}

// ------------------------------------------------------------- output GEMM
// BK=64, same staging as R10.
__global__ __launch_bounds__(256) void gemm_out(
    const unsigned short* __restrict__ A, const unsigned short* __restrict__ BT,
    const float* __restrict__ bias, float* __restrict__ of) {
  constexpr int Kd = 1024;
  __shared__ unsigned short As[2 * 128 * 32];
  __shared__ unsigned short Bs[2 * 128 * 32];
  const int tid = threadIdx.x;
  const int wave = tid >> 6, lane = tid & 63;
  const int quad = lane >> 4, l16 = lane & 15;
  const int wm = (wave & 1) * 64, wn = (wave >> 1) * 64;
  const int m0 = blockIdx.x * 128, n0 = blockIdx.y * 128;

  floatx4 acc[4][4] = {};
  const unsigned short* Ag = A + (size_t)m0 * Kd;
  const unsigned short* Bg = BT + (size_t)n0 * Kd;

  for (int k0 = 0; k0 < Kd; k0 += 64) {
    __syncthreads();
#pragma unroll
    for (int p = 0; p < 4; ++p) {
      int c = (wave * 4 + p) * 64 + lane;
      int h = c >> 9, row = (c >> 2) & 127, kp = c & 3;
      async16(Ag + (size_t)row * Kd + k0 + h * 32 + kp * 8, (char*)As + (size_t)(wave * 4 + p) * 1024);
      async16(Bg + (size_t)row * Kd + k0 + h * 32 + kp * 8, (char*)Bs + (size_t)(wave * 4 + p) * 1024);
    }
    __syncthreads();
#pragma unroll
    for (int ks = 0; ks < 2; ++ks) {
      short8 a[4], b[4];
#pragma unroll
      for (int i = 0; i < 4; ++i) {
        a[i] = *(const short8*)(As + ks * 4096 + (wm + i * 16 + l16) * 32 + quad * 8);
        b[i] = *(const short8*)(Bs + ks * 4096 + (wn + i * 16 + l16) * 32 + quad * 8);
      }
#pragma unroll
      for (int i = 0; i < 4; ++i)
#pragma unroll
        for (int j = 0; j < 4; ++j)
          acc[i][j] = __builtin_amdgcn_mfma_f32_16x16x32_bf16(a[i], b[j], acc[i][j], 0, 0, 0);
    }
  }

#pragma unroll
  for (int j = 0; j < 4; ++j) {
    int col = n0 + wn + j * 16 + l16;
    float bb = bias[col];
#pragma unroll
    for (int i = 0; i < 4; ++i) {
      int rbase = m0 + wm + i * 16 + quad * 4;
#pragma unroll
      for (int r = 0; r < 4; ++r)
        of[(size_t)(rbase + r) * 1024 + col] = acc[i][j][r] + bb;
    }
  }
}

// ---------------------------------------------------------------- launch
extern "C" void kernel_launch(void* const* d_in, const int* in_sizes, int n_in,
                              void* d_out, int out_size, void* d_ws, size_t ws_size,
                              hipStream_t stream) {
  const float* x  = (const float*)d_in[0];
  const float* Wq = (const float*)d_in[1];
  const float* bq = (const float*)d_in[2];
  const float* Wk = (const float*)d_in[3];
  const float* bk = (const float*)d_in[4];
  const float* Wv = (const float*)d_in[5];
  const float* bv = (const float*)d_in[6];
  const float* Wo = (const float*)d_in[7];
  const float* bo = (const float*)d_in[8];

  char* ws = (char*)d_ws;
  unsigned short* xb  = (unsigned short*)(ws);                 // 16 MiB
  unsigned short* wqt = (unsigned short*)(ws + (16u << 20));   // 2 MiB each, contiguous
  unsigned short* wkt = (unsigned short*)(ws + (18u << 20));
  unsigned short* wvt = (unsigned short*)(ws + (20u << 20));
  unsigned short* wot = (unsigned short*)(ws + (22u << 20));
  unsigned short* Qb  = (unsigned short*)(ws + (24u << 20));   // 16 MiB each
  unsigned short* Kb  = (unsigned short*)(ws + (40u << 20));
  unsigned short* Vtb = (unsigned short*)(ws + (56u << 20));
  unsigned short* Ob  = (unsigned short*)(ws + (72u << 20));   // total 88 MiB

  prep_kernel<<<dim3(12288), 256, 0, stream>>>(x, xb, Wq, Wk, Wv, Wo, wqt, wkt, wvt, wot);
  gemm_qkv<<<dim3(64, 24), 256, 0, stream>>>(xb, wqt, bq, bk, bv, Qb, Kb, Vtb);
  attn_kernel<<<dim3(2048), 256, 0, stream>>>(Qb, Kb, Vtb, Ob);
  gemm_out<<<dim3(64, 8), 256, 0, stream>>>(Ob, wot, bo, (float*)d_out);
}